// Round 8
// baseline (212.097 us; speedup 1.0000x reference)
//
#include <hip/hip_runtime.h>

// CrossWinAttention on MI355X (gfx950), bf16 MFMA pipeline. R8:
//  - k_attn: dual-tile ILP — each wave processes TWO key tiles concurrently
//    (independent sa/sb score chains, independent o0/o1 accumulators summed at
//    epilogue, 4-wide sle tree). Serial depth 12 -> 6 double-steps; the oacc
//    cross-tile dependency chain (24 dependent MFMAs ~1k cyc) is halved.
//    R3/R5/R6/R7 all tied at 47.5-52 us across occupancy/ILP/pipeline
//    variants -> chain depth is the remaining invariant. 768 thr (wave =
//    (n, q-group)), grid 512, launch_bounds(768,4) caps 128 VGPR;
//    WRITE_SIZE ~2 MB = no-spill check.
//  - k_prep / k_lnproj / k_out unchanged from R7.
//  - Carried: S^T trick (P stays in registers), V^T key-swizzled in LDS,
//    K from global, LN folded into GEMM epilogue, mean-over-N folded before
//    final projection, scale*log2e folded into wq/bq (exp2-only softmax),
//    v_exp_f32 + hw bf16 cvt.

typedef unsigned short u16;
typedef __bf16 bf16x8 __attribute__((ext_vector_type(8)));
typedef __bf16 bf16x4 __attribute__((ext_vector_type(4)));
typedef float  f32x16 __attribute__((ext_vector_type(16)));
typedef unsigned short u16x8 __attribute__((ext_vector_type(8)));
typedef unsigned short u16x4 __attribute__((ext_vector_type(4)));

union U8 { u16x8 u; bf16x8 b; u16x4 h[2]; };

#if __has_builtin(__builtin_amdgcn_exp2f)
#define EXP2(x) __builtin_amdgcn_exp2f(x)
#else
#define EXP2(x) exp2f(x)
#endif

__device__ __forceinline__ f32x16 mfma_bf16(bf16x8 a, bf16x8 b, f32x16 c){
  return __builtin_amdgcn_mfma_f32_32x32x16_bf16(a, b, c, 0, 0, 0);
}

// 32x32x16 bf16 fragment conventions:
//  A: m=lane&31, k=(lane>>5)*8+j ; B: n=lane&31, k=(lane>>5)*8+j
//  C/D: col=lane&31, row=(reg&3)+8*(reg>>2)+4*(lane>>5)   [verified m74/m101]
// S^T = mfma(K, Q): col = q (fixed per lane), reg axis = keys; regs 0..7 are
// exactly the PV A-slots for keys 4lh+{0-3,8-11}, regs 8..15 for +16. V^T is
// stored with the matching key swizzle so PV B-fragments are single 16B reads.

// ---------------------------------------------------------------- k_prep
// 4 blocks (one per weight) x 512 thr. Coalesced load -> LDS -> transposed
// bf16 write + parallel bias'/u reduction.
__global__ __launch_bounds__(512) void k_prep(
    const float* __restrict__ wq, const float* __restrict__ bq,
    const float* __restrict__ gq, const float* __restrict__ betq,
    const float* __restrict__ wk, const float* __restrict__ bk,
    const float* __restrict__ gk, const float* __restrict__ betk,
    const float* __restrict__ wv, const float* __restrict__ bv,
    const float* __restrict__ gv, const float* __restrict__ betv,
    const float* __restrict__ wp,
    u16* __restrict__ wqT, u16* __restrict__ wkT, u16* __restrict__ wvT, u16* __restrict__ wpT,
    float* __restrict__ bq2, float* __restrict__ bk2, float* __restrict__ bv2,
    float* __restrict__ uq2, float* __restrict__ uk2, float* __restrict__ uv2)
{
  __shared__ float wls[128*129];
  __shared__ float gls[128], bls[128];
  __shared__ float redb[512], redu[512];
  const float ALPHA_Q = 0.17677669529663687f * 1.4426950408889634f; // DH^-0.5 * log2(e)
  int wsel = blockIdx.x, tid = threadIdx.x;
  const float *w, *bb, *g, *bet; u16* wT; float *b2, *u2; float alpha;
  if (wsel == 0){ w=wq; bb=bq; g=gq; bet=betq; wT=wqT; b2=bq2; u2=uq2; alpha=ALPHA_Q; }
  else if (wsel == 1){ w=wk; bb=bk; g=gk; bet=betk; wT=wkT; b2=bk2; u2=uk2; alpha=1.f; }
  else if (wsel == 2){ w=wv; bb=bv; g=gv; bet=betv; wT=wvT; b2=bv2; u2=uv2; alpha=1.f; }
  else { w=wp; bb=nullptr; g=nullptr; bet=nullptr; wT=wpT; b2=nullptr; u2=nullptr; alpha=1.f; }

  if (tid < 128){
    gls[tid] = g ? g[tid] : 1.f;
    bls[tid] = bet ? bet[tid] : 0.f;
  }
  const float4* w4 = (const float4*)w;
  #pragma unroll
  for (int i = 0; i < 8; i++){
    int idx = tid + i*512;              // 4096 float4s
    int row = idx >> 5, c4 = (idx & 31) * 4;   // row = k, c4 = n base
    float4 x = w4[idx];
    wls[row*129 + c4 + 0] = x.x;
    wls[row*129 + c4 + 1] = x.y;
    wls[row*129 + c4 + 2] = x.z;
    wls[row*129 + c4 + 3] = x.w;
  }
  __syncthreads();
  int n = tid >> 2, qp = tid & 3;
  float sb = 0.f, su = 0.f;
  alignas(16) __bf16 tmp[32];
  #pragma unroll
  for (int kk = 0; kk < 32; kk++){
    int k2 = qp*32 + kk;
    float wv_ = wls[k2*129 + n];
    float gv_ = gls[k2];
    sb += bls[k2] * wv_;
    su += gv_ * wv_;
    tmp[kk] = (__bf16)(wv_ * gv_ * alpha);
  }
  #pragma unroll
  for (int j = 0; j < 4; j++)
    *(bf16x8*)(wT + n*128 + qp*32 + j*8) = *(bf16x8*)&tmp[j*8];
  redb[tid] = sb; redu[tid] = su;
  __syncthreads();
  if (qp == 0 && bb){
    float s = bb[n] + redb[tid] + redb[tid+1] + redb[tid+2] + redb[tid+3];
    float u = redu[tid] + redu[tid+1] + redu[tid+2] + redu[tid+3];
    b2[n] = s * alpha;
    u2[n] = u * alpha;
  }
}

// ---------------------------------------------------------------- k_lnproj
// grid 2304 = 128 (b,l) * 6 (n) * 3 (q/k/v); 256 thr (4 waves).
// Raw-x bf16 GEMM; LN applied in epilogue: y = r*z - r*m*u2[n] + b2[n].
__global__ __launch_bounds__(256) void k_lnproj(
    const float* __restrict__ qg, const float* __restrict__ kg, const float* __restrict__ vg,
    const u16* __restrict__ wqT, const u16* __restrict__ wkT, const u16* __restrict__ wvT,
    const float* __restrict__ bq2, const float* __restrict__ bk2, const float* __restrict__ bv2,
    const float* __restrict__ uq2, const float* __restrict__ uk2, const float* __restrict__ uv2,
    u16* __restrict__ qh, u16* __restrict__ kh, u16* __restrict__ vh)
{
  __shared__ alignas(16) u16 Abf[64*136];
  __shared__ float s1s[64], s2s[64];     // rs / rm
  int bid = blockIdx.x, tid = threadIdx.x;
  int which = bid % 3;
  int t = bid / 3;
  int n = t % 6, bl = t / 6;
  const float* src; const u16* wT; const float *b2, *u2; u16* dstb;
  if (which == 0){ src=qg; wT=wqT; b2=bq2; u2=uq2; dstb=qh; }
  else if (which == 1){ src=kg; wT=wkT; b2=bk2; u2=uk2; dstb=kh; }
  else { src=vg; wT=wvT; b2=bv2; u2=uv2; dstb=vh; }
  int b = bl >> 6, l = bl & 63;
  const float4* s4 = (const float4*)(src + (size_t)((b*6 + n)*64 + l)*64*128);
  int row = tid >> 2, j = tid & 3;
  float s1 = 0.f, s2 = 0.f;
  #pragma unroll
  for (int i = 0; i < 8; i++){
    float4 xv = s4[row*32 + i*4 + j];
    s1 += xv.x + xv.y + xv.z + xv.w;
    s2 += xv.x*xv.x + xv.y*xv.y + xv.z*xv.z + xv.w*xv.w;
    bf16x4 pk;
    pk[0] = (__bf16)xv.x; pk[1] = (__bf16)xv.y;
    pk[2] = (__bf16)xv.z; pk[3] = (__bf16)xv.w;
    *(bf16x4*)&Abf[row*136 + (i*4 + j)*4] = pk;
  }
  s1 += __shfl_xor(s1, 1, 64); s1 += __shfl_xor(s1, 2, 64);
  s2 += __shfl_xor(s2, 1, 64); s2 += __shfl_xor(s2, 2, 64);
  if (j == 0){
    float m = s1 * (1.f/128.f);
    float r = rsqrtf(s2 * (1.f/128.f) - m*m + 1e-5f);
    s1s[row] = r;          // rs
    s2s[row] = r * m;      // rm
  }
  __syncthreads();
  int wave = tid >> 6, lane = tid & 63, lm = lane & 31, lh = lane >> 5;
  bf16x8 bfr[8];
  const u16* wrow = wT + (32*wave + lm)*128 + lh*8;
  #pragma unroll
  for (int ks = 0; ks < 8; ks++) bfr[ks] = *(const bf16x8*)(wrow + ks*16);
  f32x16 acc0, acc1;
  #pragma unroll
  for (int r = 0; r < 16; r++){ acc0[r]=0.f; acc1[r]=0.f; }
  #pragma unroll
  for (int ks = 0; ks < 8; ks++){
    bf16x8 a0 = *(const bf16x8*)&Abf[lm*136       + ks*16 + lh*8];
    bf16x8 a1 = *(const bf16x8*)&Abf[(32+lm)*136  + ks*16 + lh*8];
    acc0 = mfma_bf16(a0, bfr[ks], acc0);
    acc1 = mfma_bf16(a1, bfr[ks], acc1);
  }
  int col = 32*wave + lm;
  float u2c = u2[col], bc = b2[col];
  u16* dst = dstb + ((size_t)(bl*4 + wave)*384 + n*64)*32 + lm;
  #pragma unroll
  for (int r = 0; r < 16; r++){
    int row0 = (r&3) + 8*(r>>2) + 4*lh;
    float y0 = s1s[row0]     * acc0[r] - s2s[row0]     * u2c + bc;
    float y1 = s1s[row0+32]  * acc1[r] - s2s[row0+32]  * u2c + bc;
    *(__bf16*)&dst[(size_t)row0*32]      = (__bf16)y0;
    *(__bf16*)&dst[(size_t)(32+row0)*32] = (__bf16)y1;
  }
}

// ---------------------------------------------------------------- k_attn
// grid 512 = (b,l)*h; 768 thr = 12 waves; wave = (n = w>>1, q-group = w&1).
// Dual-tile ILP: two key tiles in flight per wave (sa/sb, o0/o1), serial
// depth 6. K from global; V^T key-swizzled in LDS. LDS 34.3 KB.
__global__ __launch_bounds__(768, 4) void k_attn(
    const u16* __restrict__ qh, const u16* __restrict__ kh, const u16* __restrict__ vh,
    u16* __restrict__ abar)
{
  __shared__ alignas(16) u16 vts[32*408];   // V^T [dh][swizzled key], stride 408
  __shared__ float abar_s[64*32];
  int bid = blockIdx.x, tid = threadIdx.x;
  int h = bid & 3, bl = bid >> 2;
  const u16* qb = qh + (size_t)bid * (384*32);
  const u16* kb = kh + (size_t)bid * (384*32);
  const u16* vb = vh + (size_t)bid * (384*32);

  int wave = tid >> 6, lane = tid & 63, lm = lane & 31, lh = lane >> 5;
  int n = wave >> 1, qoff = (wave & 1) * 32;
  int qrow = n*64 + qoff + lm;

  // Q fragments (independent of LDS staging)
  bf16x8 qf0 = *(const bf16x8*)(qb + qrow*32 +      lh*8);
  bf16x8 qf1 = *(const bf16x8*)(qb + qrow*32 + 16 + lh*8);

  // stage V transposed + key-swizzled: key u (mod 32) at a-group perm{0,2,1,3,4,6,5,7}
  #pragma unroll
  for (int i = 0; i < 2; i++){
    int c = tid + i*768;               // 1536 16B chunks
    int key = c >> 2, part = c & 3;
    int u = key & 31, tt = key >> 5;
    int a = u >> 2;
    int anew = (a & 4) | ((a & 1) << 1) | ((a >> 1) & 1);
    int pos = tt*32 + anew*4 + (u & 3);
    u16x8 vv = *(const u16x8*)(vb + key*32 + part*8);
    #pragma unroll
    for (int jj = 0; jj < 8; jj++) vts[(part*8 + jj)*408 + pos] = vv[jj];
  }
  for (int idx = tid; idx < 2048; idx += 768) abar_s[idx] = 0.f;
  __syncthreads();

  const u16* vrow = &vts[lm*408 + 8*lh];
  const u16* krow = kb + lm*32 + lh*8;

  f32x16 o0, o1;
  #pragma unroll
  for (int r = 0; r < 16; r++){ o0[r] = 0.f; o1[r] = 0.f; }
  float sle0 = 0.f, sle1 = 0.f, sle2 = 0.f, sle3 = 0.f;

  #pragma unroll
  for (int it = 0; it < 6; it++){
    int ka = 2*it, kb2 = 2*it + 1;
    // two key tiles' K and V fetched together (independent)
    bf16x8 kfa0 = *(const bf16x8*)(krow + ka*1024);
    bf16x8 kfa1 = *(const bf16x8*)(krow + ka*1024 + 16);
    bf16x8 kfb0 = *(const bf16x8*)(krow + kb2*1024);
    bf16x8 kfb1 = *(const bf16x8*)(krow + kb2*1024 + 16);
    U8 va0, va1, vb0, vb1;
    va0.u = *(const u16x8*)(vrow + ka*32);
    va1.u = *(const u16x8*)(vrow + ka*32 + 16);
    vb0.u = *(const u16x8*)(vrow + kb2*32);
    vb1.u = *(const u16x8*)(vrow + kb2*32 + 16);
    f32x16 sa, sb;
    #pragma unroll
    for (int r = 0; r < 16; r++){ sa[r] = 0.f; sb[r] = 0.f; }
    sa = mfma_bf16(kfa0, qf0, sa);       // chain A (tile ka)
    sb = mfma_bf16(kfb0, qf0, sb);       // chain B (tile kb2) — independent
    sa = mfma_bf16(kfa1, qf1, sa);
    sb = mfma_bf16(kfb1, qf1, sb);
    U8 pa0, pa1, pb0, pb1;
    #pragma unroll
    for (int r = 0; r < 8; r++){
      float ea0 = EXP2(sa[r]);
      float ea1 = EXP2(sa[r+8]);
      float eb0 = EXP2(sb[r]);
      float eb1 = EXP2(sb[r+8]);
      sle0 += ea0; sle1 += ea1; sle2 += eb0; sle3 += eb1;
      pa0.b[r] = (__bf16)ea0;            // v_cvt_pk_bf16_f32 (RNE)
      pa1.b[r] = (__bf16)ea1;
      pb0.b[r] = (__bf16)eb0;
      pb1.b[r] = (__bf16)eb1;
    }
    o0 = mfma_bf16(pa0.b, va0.b, o0);    // two independent O accumulators
    o1 = mfma_bf16(pb0.b, vb0.b, o1);
    o0 = mfma_bf16(pa1.b, va1.b, o0);
    o1 = mfma_bf16(pb1.b, vb1.b, o1);
  }

  // total row sum for q = lm: merge 4-wide tree + lh halves, broadcast recips
  float sle = (sle0 + sle1) + (sle2 + sle3);
  sle += __shfl_xor(sle, 32, 64);
  float inv = (1.f/6.f) / sle;

  // o lane(lm,lh) reg r = O[q = qoff+(r&3)+8*(r>>2)+4*lh][dh = lm]
  #pragma unroll
  for (int r = 0; r < 16; r++){
    int q_l = (r&3) + 8*(r>>2) + 4*lh;
    float o = (o0[r] + o1[r]) * __shfl(inv, q_l, 64);
    atomicAdd(&abar_s[(qoff + q_l)*32 + lm], o);
  }
  __syncthreads();
  u16* ob = abar + (size_t)(bl*64)*128 + h*32;
  for (int idx = tid; idx < 2048; idx += 768){
    int w12 = idx >> 5, dh = idx & 31;
    *(__bf16*)&ob[(size_t)w12*128 + dh] = (__bf16)abar_s[idx];
  }
}

// ---------------------------------------------------------------- k_out
__global__ __launch_bounds__(256) void k_out(
    const u16* __restrict__ abar, const u16* __restrict__ wpT,
    const float* __restrict__ bp, const float* __restrict__ skip,
    float* __restrict__ out)
{
  __shared__ alignas(16) u16 Als[64*136];
  int tid = threadIdx.x;
  int R0 = blockIdx.x * 64;
  #pragma unroll
  for (int i = 0; i < 4; i++){
    int c = tid + i*256;
    int row = c >> 4, part = c & 15;
    *(u16x8*)&Als[row*136 + part*8] = *(const u16x8*)(abar + (size_t)(R0+row)*128 + part*8);
  }
  __syncthreads();
  int wave = tid >> 6, lane = tid & 63, lm = lane & 31, lh = lane >> 5;
  bf16x8 bfr[8];
  const u16* wrow = wpT + (32*wave + lm)*128 + lh*8;
  #pragma unroll
  for (int ks = 0; ks < 8; ks++) bfr[ks] = *(const bf16x8*)(wrow + ks*16);
  f32x16 acc0, acc1;
  #pragma unroll
  for (int r = 0; r < 16; r++){ acc0[r]=0.f; acc1[r]=0.f; }
  #pragma unroll
  for (int ks = 0; ks < 8; ks++){
    bf16x8 a0 = *(const bf16x8*)&Als[lm*136      + ks*16 + lh*8];
    bf16x8 a1 = *(const bf16x8*)&Als[(32+lm)*136 + ks*16 + lh*8];
    acc0 = mfma_bf16(a0, bfr[ks], acc0);
    acc1 = mfma_bf16(a1, bfr[ks], acc1);
  }
  float bias = bp[32*wave + lm];
  #pragma unroll
  for (int r = 0; r < 16; r++){
    int row0 = (r&3) + 8*(r>>2) + 4*lh;
    size_t f0 = (size_t)(R0 + row0)*128 + 32*wave + lm;
    out[f0] = acc0[r] + bias + skip[f0];
    size_t f1 = (size_t)(R0 + 32 + row0)*128 + 32*wave + lm;
    out[f1] = acc1[r] + bias + skip[f1];
  }
}

// ---------------------------------------------------------------- launch
extern "C" void kernel_launch(void* const* d_in, const int* in_sizes, int n_in,
                              void* d_out, int out_size, void* d_ws, size_t ws_size,
                              hipStream_t stream)
{
  const float* q    = (const float*)d_in[0];
  const float* k    = (const float*)d_in[1];
  const float* v    = (const float*)d_in[2];
  const float* skip = (const float*)d_in[3];
  const float* gq   = (const float*)d_in[4];
  const float* betq = (const float*)d_in[5];
  const float* gk   = (const float*)d_in[6];
  const float* betk = (const float*)d_in[7];
  const float* gv   = (const float*)d_in[8];
  const float* betv = (const float*)d_in[9];
  const float* wq   = (const float*)d_in[10];
  const float* bq   = (const float*)d_in[11];
  const float* wk   = (const float*)d_in[12];
  const float* bk   = (const float*)d_in[13];
  const float* wv   = (const float*)d_in[14];
  const float* bv   = (const float*)d_in[15];
  const float* wp   = (const float*)d_in[16];
  const float* bp   = (const float*)d_in[17];
  float* out = (float*)d_out;

  char* ws = (char*)d_ws;
  u16* wqT = (u16*)ws;                 // 16384 u16 each
  u16* wkT = wqT + 16384;
  u16* wvT = wkT + 16384;
  u16* wpT = wvT + 16384;
  float* bq2 = (float*)(ws + 131072);  // 128 f32 each
  float* bk2 = bq2 + 128;
  float* bv2 = bk2 + 128;
  float* uq2 = bv2 + 128;
  float* uk2 = uq2 + 128;
  float* uv2 = uk2 + 128;
  u16* qh = (u16*)(ws + 134144);       // [128][4][384][32] bf16 = 12.58 MB each
  u16* kh = qh + 6291456;
  u16* vh = kh + 6291456;
  u16* abar = vh + 6291456;            // [8192][128] bf16 = 2 MB

  k_prep  <<<4,    512, 0, stream>>>(wq,bq,gq,betq, wk,bk,gk,betk, wv,bv,gv,betv, wp,
                                     wqT,wkT,wvT,wpT, bq2,bk2,bv2, uq2,uk2,uv2);
  k_lnproj<<<2304, 256, 0, stream>>>(q,k,v, wqT,wkT,wvT, bq2,bk2,bv2, uq2,uk2,uv2, qh,kh,vh);
  k_attn  <<<512,  768, 0, stream>>>(qh,kh,vh, abar);
  k_out   <<<128,  256, 0, stream>>>(abar, wpT, bp, skip, out);
}